// Round 1
// baseline (566.083 us; speedup 1.0000x reference)
//
#include <hip/hip_runtime.h>
#include <cstdint>
#include <cstddef>

// ============================================================================
// SSD forward (image 7 only) + NMS, all fp32.
// Workspace layout (bytes), total ~33.7 MB:
//   h1   @ 0         (16.8MB)   -- reused later: part @0 (4MB), h4t @4MB (1MB)
//   h2   @ 16777216  (8.4MB)
//   h3   @ 25165824  (4.2MB)
//   wr2/wr3/wr4/wh, then small NMS buffers (see kernel_launch)
// ============================================================================

// ---------------- weight repack: w[co][ci][3][3] -> wr[(ci*9+tap)*COUT+co] ---
__global__ __launch_bounds__(256) void k_repack_w(const float* __restrict__ w,
                                                  float* __restrict__ wr,
                                                  int CIN, int COUT, int total) {
  int idx = blockIdx.x * 256 + threadIdx.x;
  if (idx >= total) return;
  int co = idx % COUT;
  int r  = idx / COUT;
  int ci = r / 9;
  int tap = r % 9;
  wr[idx] = w[(co * CIN + ci) * 9 + tap];
}

// head weights: wh[(tap*25+o)*256+ci], o<4 = reg rows, o>=4 = cls rows
__global__ __launch_bounds__(256) void k_repack_head(const float* __restrict__ regw,
                                                     const float* __restrict__ clsw,
                                                     float* __restrict__ wh) {
  int idx = blockIdx.x * 256 + threadIdx.x;
  if (idx >= 9 * 25 * 256) return;
  int ci = idx & 255;
  int r  = idx >> 8;
  int tap = r / 25;
  int o   = r % 25;
  wh[idx] = (o < 4) ? regw[(o * 256 + ci) * 9 + tap]
                    : clsw[((o - 4) * 256 + ci) * 9 + tap];
}

// ---------------- conv1: 3->64, 512->256, stride 2, SAME(pad lo 0 hi 1) ------
__global__ __launch_bounds__(256) void k_conv1(const float* __restrict__ x,
                                               const float* __restrict__ w,
                                               const float* __restrict__ b,
                                               float* __restrict__ out) {
  __shared__ float in_t[3][33][33];
  const int tx = threadIdx.x, ty = threadIdx.y;
  const int tid = ty * 16 + tx;
  const int ox0 = blockIdx.x * 16, oy0 = blockIdx.y * 16;
  for (int idx = tid; idx < 3 * 33 * 33; idx += 256) {
    int ci = idx / 1089, rem = idx % 1089;
    int r = rem / 33, c = rem % 33;
    int iy = oy0 * 2 + r, ix = ox0 * 2 + c;
    float v = 0.f;
    if (iy < 512 && ix < 512) v = x[(size_t)ci * 262144 + iy * 512 + ix];
    in_t[ci][r][c] = v;
  }
  __syncthreads();
  float rin[27];
#pragma unroll
  for (int ci = 0; ci < 3; ++ci)
#pragma unroll
    for (int kh = 0; kh < 3; ++kh)
#pragma unroll
      for (int kw = 0; kw < 3; ++kw)
        rin[ci * 9 + kh * 3 + kw] = in_t[ci][2 * ty + kh][2 * tx + kw];
  const int oy = oy0 + ty, ox = ox0 + tx;
  for (int co = 0; co < 64; ++co) {   // co uniform -> weights via s_load
    float a = 0.f;
#pragma unroll
    for (int k = 0; k < 27; ++k) a = fmaf(w[co * 27 + k], rin[k], a);
    out[(size_t)co * 65536 + oy * 256 + ox] = fmaxf(a + b[co], 0.f);
  }
}

// ---------------- generic stride-2 3x3 conv, SAME(pad lo 0 hi 1) -------------
// Block: 256 thr = 4 co-groups (one wave each, wave-uniform cout) x 64 lanes.
// Each thread: SPT spatial positions x COPT couts. Weights repacked so a
// co-group's 8 weights are contiguous -> scalar loads (readfirstlane).
template <int CIN, int COUT, int HIN, int WIN, int SH, int SW, int SPT,
          int COPT, int CIT, int KSPLIT>
__global__ __launch_bounds__(256) void conv_s2(const float* __restrict__ in,
                                               const float* __restrict__ wr,
                                               const float* __restrict__ bias,
                                               float* __restrict__ out) {
  constexpr int HOUT = HIN / 2, WOUT = WIN / 2;
  constexpr int IH = SH * 2 + 1, IW = SW * 2 + 1;
  constexpr int COT = 4 * COPT;
  static_assert(SH * SW == 64 * SPT, "positions = 64*SPT");
  __shared__ float in_t[CIT][IH][IW];

  const int tid = threadIdx.x;
  const int g   = tid >> 6;
  const int gu  = __builtin_amdgcn_readfirstlane(g);
  const int lp  = tid & 63;

  constexpr int ntx = WOUT / SW;
  const int bx = blockIdx.x % ntx, by = blockIdx.x / ntx;
  const int ox0 = bx * SW, oy0 = by * SH;
  const int co_blk = blockIdx.y * COT;
  const int ci_begin = (KSPLIT > 1) ? blockIdx.z * (CIN / KSPLIT) : 0;
  const int ci_end   = ci_begin + CIN / KSPLIT;

  int py[SPT], px[SPT];
#pragma unroll
  for (int s = 0; s < SPT; ++s) {
    int pos = lp + s * 64;
    py[s] = pos / SW;
    px[s] = pos % SW;
  }

  float acc[SPT][COPT] = {};

  for (int cib = ci_begin; cib < ci_end; cib += CIT) {
    __syncthreads();
    for (int idx = tid; idx < CIT * IH * IW; idx += 256) {
      int ci = idx / (IH * IW), rem = idx % (IH * IW);
      int r = rem / IW, c = rem % IW;
      int iy = oy0 * 2 + r, ix = ox0 * 2 + c;
      float v = 0.f;
      if (iy < HIN && ix < WIN)
        v = in[(size_t)(cib + ci) * HIN * WIN + iy * WIN + ix];
      in_t[ci][r][c] = v;
    }
    __syncthreads();
    for (int ci = 0; ci < CIT; ++ci) {
#pragma unroll
      for (int kh = 0; kh < 3; ++kh)
#pragma unroll
        for (int kw = 0; kw < 3; ++kw) {
          const float* wp =
              &wr[(size_t)((cib + ci) * 9 + kh * 3 + kw) * COUT + co_blk +
                  gu * COPT];
          float wv[COPT];
#pragma unroll
          for (int c = 0; c < COPT; ++c) wv[c] = wp[c];
#pragma unroll
          for (int s = 0; s < SPT; ++s) {
            float v = in_t[ci][2 * py[s] + kh][2 * px[s] + kw];
#pragma unroll
            for (int c = 0; c < COPT; ++c)
              acc[s][c] = fmaf(v, wv[c], acc[s][c]);
          }
        }
    }
  }

#pragma unroll
  for (int s = 0; s < SPT; ++s) {
    int oy = oy0 + py[s], ox = ox0 + px[s];
#pragma unroll
    for (int c = 0; c < COPT; ++c) {
      int co = co_blk + gu * COPT + c;
      if constexpr (KSPLIT > 1) {
        out[((size_t)blockIdx.z * COUT + co) * (HOUT * WOUT) + oy * WOUT + ox] =
            acc[s][c];
      } else {
        out[(size_t)co * (HOUT * WOUT) + oy * WOUT + ox] =
            fmaxf(acc[s][c] + bias[co], 0.f);
      }
    }
  }
}

// ---------------- combine conv4 K-split partials + bias + relu, write NHWC ---
__global__ __launch_bounds__(256) void k_combine(const float* __restrict__ part,
                                                 const float* __restrict__ b,
                                                 float* __restrict__ h4t) {
  int co = blockIdx.x;  // 0..255
  float bb = b[co];
  for (int k2 = 0; k2 < 4; ++k2) {
    int pos = threadIdx.x + k2 * 256;
    float v = part[(size_t)(0 * 256 + co) * 1024 + pos] +
              part[(size_t)(1 * 256 + co) * 1024 + pos] +
              part[(size_t)(2 * 256 + co) * 1024 + pos] +
              part[(size_t)(3 * 256 + co) * 1024 + pos];
    h4t[(size_t)pos * 256 + co] = fmaxf(v + bb, 0.f);
  }
}

// ---------------- head: reg(4)+cls(21) stride-1 conv + softmax/max/argmax ----
// One block per spatial position (1024). Thread t = input channel t.
__global__ __launch_bounds__(256) void k_head(const float* __restrict__ h4t,
                                              const float* __restrict__ wh,
                                              const float* __restrict__ regb,
                                              const float* __restrict__ clsb,
                                              float* __restrict__ locs,
                                              float* __restrict__ confs,
                                              float* __restrict__ scores,
                                              float* __restrict__ labelsF) {
  const int pos = blockIdx.x;
  const int py = pos >> 5, px = pos & 31;
  const int t = threadIdx.x;
  float part[25] = {};
#pragma unroll
  for (int kh = 0; kh < 3; ++kh) {
    int iy = py + kh - 1;
    if (iy < 0 || iy > 31) continue;  // block-uniform
#pragma unroll
    for (int kw = 0; kw < 3; ++kw) {
      int ix = px + kw - 1;
      if (ix < 0 || ix > 31) continue;
      int tap = kh * 3 + kw;
      float v = h4t[(size_t)(iy * 32 + ix) * 256 + t];
      const float* wp = wh + (size_t)tap * 25 * 256 + t;
#pragma unroll
      for (int o = 0; o < 25; ++o)
        part[o] = fmaf(v, wp[(size_t)o * 256], part[o]);
    }
  }
  // wave butterfly reduce (64 lanes)
#pragma unroll
  for (int o = 0; o < 25; ++o) {
#pragma unroll
    for (int d = 1; d < 64; d <<= 1) part[o] += __shfl_xor(part[o], d);
  }
  __shared__ float red[4][25];
  __shared__ float yv[25];
  const int wv = t >> 6, ln = t & 63;
  if (ln == 0) {
#pragma unroll
    for (int o = 0; o < 25; ++o) red[wv][o] = part[o];
  }
  __syncthreads();
  if (t < 25) {
    float y = red[0][t] + red[1][t] + red[2][t] + red[3][t];
    y += (t < 4) ? regb[t] : clsb[t - 4];
    if (t < 4) locs[(size_t)pos * 4 + t] = y;
    else       confs[(size_t)pos * 21 + (t - 4)] = y;
    yv[t] = y;
  }
  __syncthreads();
  if (t == 0) {
    float m = yv[4];
    int lab = 0;
    for (int j = 1; j < 21; ++j)
      if (yv[4 + j] > m) { m = yv[4 + j]; lab = j; }  // first-max semantics
    float s = 0.f;
    for (int j = 0; j < 21; ++j) s += expf(yv[4 + j] - m);
    scores[pos] = 1.f / s;   // max softmax prob
    labelsF[pos] = (float)lab;
  }
}

// ---------------- stable descending bitonic sort of 1024 scores --------------
__global__ __launch_bounds__(512) void k_sort(const float* __restrict__ scores,
                                              const float* __restrict__ locs,
                                              int* __restrict__ order,
                                              float* __restrict__ ssc,
                                              float* __restrict__ bsrt,
                                              unsigned long long* __restrict__ vbits) {
  __shared__ float sk[1024];
  __shared__ int   si[1024];
  const int t = threadIdx.x;
  sk[t] = scores[t];           si[t] = t;
  sk[t + 512] = scores[t + 512]; si[t + 512] = t + 512;
  for (int k = 2; k <= 1024; k <<= 1) {
    for (int j = k >> 1; j > 0; j >>= 1) {
      __syncthreads();
      int i1 = ((t / j) * (2 * j)) + (t % j);
      int i2 = i1 + j;
      bool up = (i1 & k) == 0;
      float sa = sk[i1], sb = sk[i2];
      int ia = si[i1], ib = si[i2];
      bool b_before_a = (sb > sa) || (sb == sa && ib < ia);
      bool a_before_b = (sa > sb) || (sa == sb && ia < ib);
      bool sw = up ? b_before_a : a_before_b;
      if (sw) { sk[i1] = sb; sk[i2] = sa; si[i1] = ib; si[i2] = ia; }
    }
  }
  __syncthreads();
  for (int i = t; i < 1024; i += 512) {
    int oi = si[i];
    order[i] = oi;
    ssc[i] = sk[i];
    ((float4*)bsrt)[i] = ((const float4*)locs)[oi];
  }
  if (t < 16) {  // validity bits (score > SCORE_THR), sorted order
    unsigned long long w = 0;
    for (int b2 = 0; b2 < 64; ++b2)
      if (sk[t * 64 + b2] > 0.04f) w |= (1ull << b2);
    vbits[t] = w;
  }
}

// ---------------- pairwise IoU suppression bitmask (1024x1024 bits) ----------
__global__ __launch_bounds__(256) void k_mask(const float* __restrict__ bsrt,
                                              unsigned long long* __restrict__ mask) {
  __shared__ float4 sb[1024];
  const int t = threadIdx.x;
  for (int idx = t; idx < 1024; idx += 256)
    sb[idx] = ((const float4*)bsrt)[idx];
  __syncthreads();
  const int i = blockIdx.x * 16 + (t & 15);
  const int w = t >> 4;
  float4 bi = sb[i];
  float ai = (bi.z - bi.x) * (bi.w - bi.y);
  unsigned long long bits = 0;
  for (int jj = 0; jj < 64; ++jj) {
    float4 bj = sb[w * 64 + jj];
    float aj = (bj.z - bj.x) * (bj.w - bj.y);
    float ltx = fmaxf(bi.x, bj.x), lty = fmaxf(bi.y, bj.y);
    float rbx = fminf(bi.z, bj.z), rby = fminf(bi.w, bj.w);
    float inter = fmaxf(rbx - ltx, 0.f) * fmaxf(rby - lty, 0.f);
    float uni = ai + aj - inter;
    float iou = inter / (uni + 1e-9f);
    if (iou > 0.5f) bits |= (1ull << jj);
  }
  mask[(size_t)i * 16 + w] = bits;
}

// ---------------- sequential greedy NMS scan (wave 0, LDS-staged halves) -----
__global__ __launch_bounds__(256) void k_scan(const unsigned long long* __restrict__ mask,
                                              const unsigned long long* __restrict__ vbits,
                                              unsigned long long* __restrict__ keepb) {
  __shared__ unsigned long long m_lds[512 * 16];  // exactly 64 KB
  const int t = threadIdx.x;
  unsigned long long keepm = 0, vw = 0;
  if (t < 16) vw = vbits[t];
  for (int ph = 0; ph < 2; ++ph) {
    __syncthreads();
    for (int idx = t; idx < 8192; idx += 256) m_lds[idx] = mask[ph * 8192 + idx];
    __syncthreads();
    if (t < 64) {
      for (int ii = 0; ii < 512; ++ii) {
        int i = ph * 512 + ii;
        unsigned long long row = (t < 16) ? m_lds[ii * 16 + t] : 0ull;
        bool hit = (row & keepm) != 0ull;
        bool sup = __any(hit);
        int wsel = i >> 6, bsel = i & 63;
        unsigned long long vword = __shfl(vw, wsel);
        bool vv = (vword >> bsel) & 1ull;
        bool kp = vv && !sup;
        if (kp && t == wsel) keepm |= (1ull << bsel);
      }
    }
  }
  __syncthreads();
  if (t < 16) keepb[t] = keepm;
}

// ---------------- final gather into d_out ------------------------------------
// layout: boxes[1024*4] | labels[1024] | scores[1024] | confs[1024*21]
__global__ __launch_bounds__(256) void k_gather(const unsigned long long* __restrict__ keepb,
                                                const int* __restrict__ order,
                                                const float* __restrict__ ssc,
                                                const float* __restrict__ locs,
                                                const float* __restrict__ confs,
                                                const float* __restrict__ labelsF,
                                                float* __restrict__ out) {
  int i = blockIdx.x * 256 + threadIdx.x;  // 0..1023
  bool k = (keepb[i >> 6] >> (i & 63)) & 1ull;
  int oi = order[i];
  float4 bx = k ? ((const float4*)locs)[oi] : make_float4(-1.f, -1.f, -1.f, -1.f);
  ((float4*)out)[i] = bx;
  out[4096 + i] = k ? labelsF[oi] : 0.f;
  out[5120 + i] = k ? ssc[i] : -1.f;
  float* oc = out + 6144 + (size_t)i * 21;
  const float* cc = confs + (size_t)oi * 21;
#pragma unroll
  for (int c = 0; c < 21; ++c) oc[c] = k ? cc[c] : -1.f;
}

// ============================================================================
extern "C" void kernel_launch(void* const* d_in, const int* in_sizes, int n_in,
                              void* d_out, int out_size, void* d_ws, size_t ws_size,
                              hipStream_t stream) {
  const float* x    = (const float*)d_in[0] + (size_t)7 * 3 * 512 * 512;  // image 7 only
  const float* w1   = (const float*)d_in[1];
  const float* b1   = (const float*)d_in[2];
  const float* w2   = (const float*)d_in[3];
  const float* b2   = (const float*)d_in[4];
  const float* w3   = (const float*)d_in[5];
  const float* b3   = (const float*)d_in[6];
  const float* w4   = (const float*)d_in[7];
  const float* b4   = (const float*)d_in[8];
  const float* regw = (const float*)d_in[9];
  const float* regb = (const float*)d_in[10];
  const float* clsw = (const float*)d_in[11];
  const float* clsb = (const float*)d_in[12];
  float* out = (float*)d_out;
  char* ws = (char*)d_ws;

  float* h1    = (float*)(ws + 0);
  float* part  = (float*)(ws + 0);         // reuse h1 region (h1 dead by conv4)
  float* h4t   = (float*)(ws + 4194304);   // reuse h1 region
  float* h2    = (float*)(ws + 16777216);
  float* h3    = (float*)(ws + 25165824);
  float* wr2   = (float*)(ws + 29360128);
  float* wr3   = (float*)(ws + 29655040);
  float* wr4   = (float*)(ws + 30834688);
  float* wh    = (float*)(ws + 33193984);
  float* locs  = (float*)(ws + 33424384);
  float* confs = (float*)(ws + 33440768);
  float* scores  = (float*)(ws + 33526784);
  float* labelsF = (float*)(ws + 33530880);
  int*   order   = (int*)  (ws + 33534976);
  float* ssc     = (float*)(ws + 33539072);
  float* bsrt    = (float*)(ws + 33543168);
  unsigned long long* mask  = (unsigned long long*)(ws + 33559552);
  unsigned long long* vbits = (unsigned long long*)(ws + 33690624);
  unsigned long long* keepb = (unsigned long long*)(ws + 33690752);

  k_repack_w<<<288, 256, 0, stream>>>(w2, wr2, 64, 128, 73728);
  k_repack_w<<<1152, 256, 0, stream>>>(w3, wr3, 128, 256, 294912);
  k_repack_w<<<2304, 256, 0, stream>>>(w4, wr4, 256, 256, 589824);
  k_repack_head<<<225, 256, 0, stream>>>(regw, clsw, wh);

  k_conv1<<<dim3(16, 16), dim3(16, 16), 0, stream>>>(x, w1, b1, h1);

  conv_s2<64, 128, 256, 256, 8, 16, 2, 8, 8, 1>
      <<<dim3(128, 4, 1), 256, 0, stream>>>(h1, wr2, b2, h2);
  conv_s2<128, 256, 128, 128, 8, 8, 1, 8, 8, 1>
      <<<dim3(64, 8, 1), 256, 0, stream>>>(h2, wr3, b3, h3);
  conv_s2<256, 256, 64, 64, 8, 8, 1, 8, 8, 4>
      <<<dim3(16, 8, 4), 256, 0, stream>>>(h3, wr4, (const float*)nullptr, part);

  k_combine<<<256, 256, 0, stream>>>(part, b4, h4t);
  k_head<<<1024, 256, 0, stream>>>(h4t, wh, regb, clsb, locs, confs, scores, labelsF);

  k_sort<<<1, 512, 0, stream>>>(scores, locs, order, ssc, bsrt, vbits);
  k_mask<<<64, 256, 0, stream>>>(bsrt, mask);
  k_scan<<<1, 256, 0, stream>>>(mask, vbits, keepb);
  k_gather<<<4, 256, 0, stream>>>(keepb, order, ssc, locs, confs, labelsF, out);
}